// Round 1
// baseline (238.536 us; speedup 1.0000x reference)
//
#include <hip/hip_runtime.h>
#include <math.h>

// Problem shape (fixed by the reference): x = (B=4, S=8192, D=1024) float32.
// out[b,s,d] = x[b,s,d] + pos[s,d]
//   pos[s,d] = sin(s / 10000^((d+1)/D)) if d even, cos(...) if d odd.
#define PE_S 8192
#define PE_D 1024
#define PE_B 4

typedef float f32x4 __attribute__((ext_vector_type(4)));

// One thread per (s, d-quad). KEY CHANGE vs previous version: the 4 batch-plane
// loads are issued FIRST (entry basic block, no control flow above them), so
// they are all in flight while the ocml sinf/cosf Payne-Hanek chain (several
// hundred dependent cycles for args up to ~8100 rad) executes. Previously the
// transcendentals came first and the loop did load->wait->add->store per
// plane, serializing a VALU-latency phase with a memory-latency phase
// (VALUBusy 11%, HBM 39% of achievable, VGPR=28 => ~1 load in flight).
// Stores are non-temporal: `out` is never re-read, and keeping the 128 MiB
// output stream out of the Infinity Cache leaves room for x (128 MiB) to stay
// L3-resident across dispatches (FETCH_SIZE was already showing ~50% L3 hits).
__global__ __launch_bounds__(256) void position_encoder_kernel(
    const float* __restrict__ x, float* __restrict__ out) {
    const int tid = blockIdx.x * blockDim.x + threadIdx.x;  // 0 .. S*D/4-1
    const int d4  = tid & (PE_D / 4 - 1);                   // 0..255
    const int s   = tid >> 8;                               // 0..8191
    const int d0  = d4 << 2;                                // aligned quad start

    const size_t base  = (size_t)s * PE_D + (size_t)d0;
    const size_t plane = (size_t)PE_S * PE_D;

    // ---- issue all 4 independent loads up front (4 KiB in flight per wave) ----
    const f32x4 v0 = *reinterpret_cast<const f32x4*>(x + 0 * plane + base);
    const f32x4 v1 = *reinterpret_cast<const f32x4*>(x + 1 * plane + base);
    const f32x4 v2 = *reinterpret_cast<const f32x4*>(x + 2 * plane + base);
    const f32x4 v3 = *reinterpret_cast<const f32x4*>(x + 3 * plane + base);

    // ---- transcendental chain overlaps the memory latency ----
    const float fs = (float)s;
    // pf_j = s * 10000^(-(j+1)/D) = s * 2^((j+1) * a2),  a2 = -log2(10000)/1024
    const float a2 = -0.012976281620653760f;
    const float w0 = exp2f((float)(d0 + 1) * a2);
    const float w1 = exp2f((float)(d0 + 2) * a2);
    const float w2 = exp2f((float)(d0 + 3) * a2);
    const float w3 = exp2f((float)(d0 + 4) * a2);

    // d0 even -> sin, d0+1 odd -> cos, d0+2 even -> sin, d0+3 odd -> cos.
    // libm sinf/cosf (ocml): args reach ~8100 rad, need real range reduction.
    f32x4 p;
    p.x = sinf(fs * w0);
    p.y = cosf(fs * w1);
    p.z = sinf(fs * w2);
    p.w = cosf(fs * w3);

    // ---- adds + non-temporal stores at the end ----
    f32x4 o0 = v0 + p;
    f32x4 o1 = v1 + p;
    f32x4 o2 = v2 + p;
    f32x4 o3 = v3 + p;

    __builtin_nontemporal_store(o0, reinterpret_cast<f32x4*>(out + 0 * plane + base));
    __builtin_nontemporal_store(o1, reinterpret_cast<f32x4*>(out + 1 * plane + base));
    __builtin_nontemporal_store(o2, reinterpret_cast<f32x4*>(out + 2 * plane + base));
    __builtin_nontemporal_store(o3, reinterpret_cast<f32x4*>(out + 3 * plane + base));
}

extern "C" void kernel_launch(void* const* d_in, const int* in_sizes, int n_in,
                              void* d_out, int out_size, void* d_ws, size_t ws_size,
                              hipStream_t stream) {
    const float* x = (const float*)d_in[0];
    float* out = (float*)d_out;

    const int threads = 256;
    const int total_quads = PE_S * PE_D / 4;       // 2,097,152 threads
    const int blocks = total_quads / threads;      // 8192 blocks
    position_encoder_kernel<<<blocks, threads, 0, stream>>>(x, out);
}

// Round 2
// 218.656 us; speedup vs baseline: 1.0909x; 1.0909x over previous
//
#include <hip/hip_runtime.h>
#include <math.h>

// Problem shape (fixed by the reference): x = (B=4, S=8192, D=1024) float32.
// out[b,s,d] = x[b,s,d] + pos[s,d]
//   pos[s,d] = sin(s / 10000^((d+1)/D)) if d even, cos(...) if d odd.
#define PE_S 8192
#define PE_D 1024
#define PE_B 4

typedef float f32x4 __attribute__((ext_vector_type(4)));

// Native-trig positional value. v_sin_f32/v_cos_f32 take REVOLUTIONS
// (D = sin(S0*2pi)); valid after fract-reduction. wrev = 10000^-((j+1)/D) / (2pi)
// comes from ONE v_exp_f32 by folding -log2(2pi) into the exponent.
// The fmaf residual makes the s*wrev product effectively double-precision for
// the reduction, so the only error vs the previous ocml version is the ~1ulp
// hardware sin/cos itself (well under the existing 0.03 arg-sensitivity
// envelope that both we and the jax reference already sit in).
__device__ __forceinline__ float pe_sin(float fs, float wrev) {
    float t = fs * wrev;
    float r = t - floorf(t);
    r += fmaf(fs, wrev, -t);            // exact product residual
    return __builtin_amdgcn_sinf(r);    // sin(2*pi*r)
}
__device__ __forceinline__ float pe_cos(float fs, float wrev) {
    float t = fs * wrev;
    float r = t - floorf(t);
    r += fmaf(fs, wrev, -t);
    return __builtin_amdgcn_cosf(r);    // cos(2*pi*r)
}

// One thread per float4 of the FULL (B,S,D) tensor, linear tid -> byte-linear
// read and write streams (identical access pattern to the 6.3 TB/s copy
// ubench: 2 streams, no plane-strided gather). Trig is recomputed per plane
// (4x more trig than the quad-reuse version) but is now ~8 branch-free
// TRANS/VALU ops per element: no ocml calls, no divergent slow paths, no
// basic-block boundaries blocking the scheduler. Each wave = 1 load
// (overlapped with the short trig chain) + add + 1 store.
__global__ __launch_bounds__(256) void position_encoder_kernel(
    const float* __restrict__ x, float* __restrict__ out) {
    const int tid = blockIdx.x * blockDim.x + threadIdx.x;  // 0 .. B*S*D/4-1
    const int d4  = tid & (PE_D / 4 - 1);                   // 0..255
    const int s   = (tid >> 8) & (PE_S - 1);                // 0..8191
    const int d0  = d4 << 2;

    const float fs = (float)s;
    const float A2 = -0.012976281620653760f;  // -log2(10000)/1024
    const float C  = -2.6514961294723187f;    // -log2(2*pi)

    // wrev_k = 2^((d0+k)*A2 + C) = 10000^-((d0+k)/1024) / (2*pi)
    const float w0 = exp2f(fmaf((float)(d0 + 1), A2, C));
    const float w1 = exp2f(fmaf((float)(d0 + 2), A2, C));
    const float w2 = exp2f(fmaf((float)(d0 + 3), A2, C));
    const float w3 = exp2f(fmaf((float)(d0 + 4), A2, C));

    const size_t off = (size_t)tid * 4;
    const f32x4 v = *reinterpret_cast<const f32x4*>(x + off);

    f32x4 o;
    o.x = v.x + pe_sin(fs, w0);   // d0   even -> sin
    o.y = v.y + pe_cos(fs, w1);   // d0+1 odd  -> cos
    o.z = v.z + pe_sin(fs, w2);   // d0+2 even -> sin
    o.w = v.w + pe_cos(fs, w3);   // d0+3 odd  -> cos
    *reinterpret_cast<f32x4*>(out + off) = o;
}

extern "C" void kernel_launch(void* const* d_in, const int* in_sizes, int n_in,
                              void* d_out, int out_size, void* d_ws, size_t ws_size,
                              hipStream_t stream) {
    const float* x = (const float*)d_in[0];
    float* out = (float*)d_out;

    const int threads = 256;
    const int total_quads = PE_B * PE_S * PE_D / 4;  // 8,388,608 threads
    const int blocks = total_quads / threads;        // 32,768 blocks
    position_encoder_kernel<<<blocks, threads, 0, stream>>>(x, out);
}